// Round 1
// baseline (877.752 us; speedup 1.0000x reference)
//
#include <hip/hip_runtime.h>

#define Bdim 8
#define Ddim 64
#define Hdim 384
#define Wdim 512

__global__ __launch_bounds__(256) void resample2d_kernel(
    const float* __restrict__ img,   // (B, D, H, W)
    const float* __restrict__ flow,  // (B, 2, H, W)
    float* __restrict__ out)         // (B, D, H, W)
{
    const int HW = Hdim * Wdim;
    int idx = blockIdx.x * blockDim.x + threadIdx.x;  // over B*H*W
    if (idx >= Bdim * HW) return;

    int w  = idx % Wdim;
    int hw = idx % HW;
    int h  = hw / Wdim;
    int b  = idx / HW;

    // flow: u = flow[b,0,h,w], v = flow[b,1,h,w]
    float u = flow[(size_t)b * 2 * HW + hw];
    float v = flow[(size_t)b * 2 * HW + HW + hw];

    float fx = fminf(fmaxf((float)w + u, 0.0f), (float)(Wdim - 1));
    float fy = fminf(fmaxf((float)h + v, 0.0f), (float)(Hdim - 1));
    float x0f = floorf(fx);
    float y0f = floorf(fy);
    float wx = fx - x0f;
    float wy = fy - y0f;
    int x0 = (int)x0f;
    int y0 = (int)y0f;
    int x1 = min(x0 + 1, Wdim - 1);
    int y1 = min(y0 + 1, Hdim - 1);

    float w00 = (1.0f - wy) * (1.0f - wx);
    float w01 = (1.0f - wy) * wx;
    float w10 = wy * (1.0f - wx);
    float w11 = wy * wx;

    int i00 = y0 * Wdim + x0;
    int i01 = y0 * Wdim + x1;
    int i10 = y1 * Wdim + x0;
    int i11 = y1 * Wdim + x1;

    const float* base  = img + (size_t)b * Ddim * HW;
    float*       obase = out + (size_t)b * Ddim * HW + hw;

    #pragma unroll 4
    for (int d = 0; d < Ddim; ++d) {
        const float* p = base + (size_t)d * HW;
        float r = p[i00] * w00 + p[i01] * w01 + p[i10] * w10 + p[i11] * w11;
        obase[(size_t)d * HW] = r;
    }
}

extern "C" void kernel_launch(void* const* d_in, const int* in_sizes, int n_in,
                              void* d_out, int out_size, void* d_ws, size_t ws_size,
                              hipStream_t stream) {
    const float* img  = (const float*)d_in[0];
    const float* flow = (const float*)d_in[1];
    float* out = (float*)d_out;

    const int total = Bdim * Hdim * Wdim;  // 1,572,864 threads
    dim3 block(256);
    dim3 grid((total + block.x - 1) / block.x);  // 6144 blocks
    resample2d_kernel<<<grid, block, 0, stream>>>(img, flow, out);
}